// Round 3
// baseline (869.022 us; speedup 1.0000x reference)
//
#include <hip/hip_runtime.h>
#include <hip/hip_bf16.h>
#include <stdint.h>

// Problem constants (from setup_inputs)
#define HDIM 256
#define NNODE 50000
#define EFULL 500000
#define BSESS 1024
#define NPER 12
#define NROWS 12288   // BSESS * NPER

typedef __attribute__((ext_vector_type(8))) short bf16x8;
typedef __attribute__((ext_vector_type(4))) float f32x4;
typedef __attribute__((ext_vector_type(4))) unsigned short u16x4;

__device__ __forceinline__ float bf2f(unsigned short v) {
  union { unsigned u; float f; } x; x.u = ((unsigned)v) << 16; return x.f;
}
__device__ __forceinline__ unsigned short f2bf(float f) {
  union { float f; unsigned u; } x; x.f = f;
  unsigned r = x.u + 0x7fff + ((x.u >> 16) & 1);   // RNE
  return (unsigned short)(r >> 16);
}

// ---------------- small utility kernels ----------------
__global__ void k_zero_f4(float4* p, int n4) {
  int i = blockIdx.x * 256 + threadIdx.x;
  if (i < n4) p[i] = make_float4(0.f, 0.f, 0.f, 0.f);
}
__global__ void k_init_map(int* m) {
  int i = blockIdx.x * 256 + threadIdx.x;
  if (i < NNODE) m[i] = -1;
}
__global__ void k_set_map(const int* __restrict__ x, int* __restrict__ m) {
  int i = blockIdx.x * 256 + threadIdx.x;
  if (i < NROWS) atomicMax(&m[x[i] - 1], i);   // representative row id per needed node
}

// one-pass f32 -> bf16 conversion of emb + all weights (ggnn_W transposed)
#define CV_EMB   12800000
#define CV_WT    65536
#define CV_WIH   196608
#define CV_WHH   196608
#define CV_W1    65536
#define CV_W2    65536
#define CV_W3    131072
#define CV_BIAS  2304      // bih(768) bhh(768) W1b(256) W2b(256) W3b(256)
#define CV_TOTAL (CV_EMB + CV_WT + CV_WIH + CV_WHH + CV_W1 + CV_W2 + CV_W3 + CV_BIAS)
__global__ void k_conv(const float* __restrict__ emb, const float* __restrict__ gw,
                       const float* __restrict__ wih, const float* __restrict__ whh,
                       const float* __restrict__ w1, const float* __restrict__ w2,
                       const float* __restrict__ w3,
                       const float* __restrict__ bih, const float* __restrict__ bhh,
                       const float* __restrict__ w1b, const float* __restrict__ w2b,
                       const float* __restrict__ w3b,
                       unsigned short* __restrict__ embB, unsigned short* __restrict__ wtB,
                       unsigned short* __restrict__ wihB, unsigned short* __restrict__ whhB,
                       unsigned short* __restrict__ w1B, unsigned short* __restrict__ w2B,
                       unsigned short* __restrict__ w3B, unsigned short* __restrict__ biasB) {
  long idx = (long)blockIdx.x * 256 + threadIdx.x;
  if (idx < CV_EMB) { embB[idx] = f2bf(emb[idx]); return; }
  idx -= CV_EMB;
  if (idx < CV_WT) {   // WT[j][k] = W[k][j]
    int j = (int)(idx >> 8), k = (int)(idx & 255);
    wtB[idx] = f2bf(gw[k * 256 + j]); return;
  }
  idx -= CV_WT;
  if (idx < CV_WIH) { wihB[idx] = f2bf(wih[idx]); return; }
  idx -= CV_WIH;
  if (idx < CV_WHH) { whhB[idx] = f2bf(whh[idx]); return; }
  idx -= CV_WHH;
  if (idx < CV_W1)  { w1B[idx] = f2bf(w1[idx]); return; }
  idx -= CV_W1;
  if (idx < CV_W2)  { w2B[idx] = f2bf(w2[idx]); return; }
  idx -= CV_W2;
  if (idx < CV_W3)  { w3B[idx] = f2bf(w3[idx]); return; }
  idx -= CV_W3;
  if (idx < 768)        { biasB[idx] = f2bf(bih[idx]); return; }
  if (idx < 1536)       { biasB[idx] = f2bf(bhh[idx - 768]); return; }
  if (idx < 1792)       { biasB[idx] = f2bf(w1b[idx - 1536]); return; }
  if (idx < 2048)       { biasB[idx] = f2bf(w2b[idx - 1792]); return; }
  if (idx < CV_BIAS)    { biasB[idx] = f2bf(w3b[idx - 2048]); return; }
}

// scatter: S[cid] += emb_f32[src] for edges whose dst is a needed node (1 wave per edge)
__global__ void k_scatter(const int* __restrict__ fg, const int* __restrict__ map,
                          const float* __restrict__ emb, float* __restrict__ S) {
  int e = blockIdx.x * 4 + (threadIdx.x >> 6);
  int cid = map[fg[EFULL + e]];
  if (cid < 0) return;
  int src = fg[e];
  int lane = threadIdx.x & 63;
  float4 v = *(const float4*)(emb + (size_t)src * HDIM + lane * 4);
  float* s = S + (size_t)cid * HDIM + lane * 4;
  atomicAdd(s + 0, v.x);
  atomicAdd(s + 1, v.y);
  atomicAdd(s + 2, v.z);
  atomicAdd(s + 3, v.w);
}
__global__ void k_f2bf_arr(const float* __restrict__ in, unsigned short* __restrict__ out, int n) {
  int i = blockIdx.x * 256 + threadIdx.x;
  if (i < n) out[i] = f2bf(in[i]);
}
// gather per session-node row: agg row (post-GEMM, bf16) + emb row (f32 -> bf16)
__global__ void k_gather(const int* __restrict__ x, const int* __restrict__ map,
                         const unsigned short* __restrict__ A2, const float* __restrict__ emb,
                         unsigned short* __restrict__ aggC, unsigned short* __restrict__ embC) {
  int i = blockIdx.x;
  int lane = threadIdx.x;                      // 64
  int node = x[i] - 1;
  int cid = map[node];
  if (cid < 0) cid = 0;                        // defensive (cannot happen)
  *(u16x4*)(aggC + (size_t)i * HDIM + lane * 4) = *(const u16x4*)(A2 + (size_t)cid * HDIM + lane * 4);
  float4 v = *(const float4*)(emb + (size_t)node * HDIM + lane * 4);
  u16x4 o; o.x = f2bf(v.x); o.y = f2bf(v.y); o.z = f2bf(v.z); o.w = f2bf(v.w);
  *(u16x4*)(embC + (size_t)i * HDIM + lane * 4) = o;
}
// GRU elementwise: gi/gh already include biases (added in GEMM epilogue)
__global__ void k_gru(const unsigned short* __restrict__ gi, const unsigned short* __restrict__ gh,
                      const unsigned short* __restrict__ embC,
                      unsigned short* __restrict__ h2b, float* __restrict__ h2out) {
  int idx = blockIdx.x * 256 + threadIdx.x;    // i*256 + c
  size_t base = (size_t)(idx >> 8) * 768;
  int c = idx & 255;
  float ir = bf2f(gi[base + c]), iz = bf2f(gi[base + 256 + c]), inn = bf2f(gi[base + 512 + c]);
  float hr = bf2f(gh[base + c]), hz = bf2f(gh[base + 256 + c]), hn = bf2f(gh[base + 512 + c]);
  float r = 1.f / (1.f + expf(-(ir + hr)));
  float z = 1.f / (1.f + expf(-(iz + hz)));
  float n = tanhf(inn + r * hn);
  float h = fmaxf((1.f - z) * n + z * bf2f(embC[idx]), 0.f);   // relu
  h2b[idx] = f2bf(h);
  h2out[idx] = h;                               // float32 output
}
// v_n -> shin[:, 0:256]
__global__ void k_vn(const unsigned short* __restrict__ h2b, unsigned short* __restrict__ shin) {
  int idx = blockIdx.x * 256 + threadIdx.x;    // b*256 + c
  int b = idx >> 8, c = idx & 255;
  shin[(size_t)b * 512 + c] = h2b[((size_t)b * NPER + (NPER - 1)) * 256 + c];
}
// alpha[i] = q_b + sum_c q[c] * sigmoid(t1[batch[i],c] + t2[i,c])  (1 wave per row)
__global__ void k_alpha(const unsigned short* __restrict__ t1, const unsigned short* __restrict__ t2,
                        const int* __restrict__ batch, const float* __restrict__ qw,
                        const float* __restrict__ qb, float* __restrict__ alpha) {
  int i = blockIdx.x, lane = threadIdx.x;
  int b = batch[i];
  u16x4 a = *(const u16x4*)(t1 + (size_t)b * HDIM + lane * 4);
  u16x4 c = *(const u16x4*)(t2 + (size_t)i * HDIM + lane * 4);
  float4 q = *(const float4*)(qw + lane * 4);
  float p = 0.f;
  p += q.x / (1.f + expf(-(bf2f(a.x) + bf2f(c.x))));
  p += q.y / (1.f + expf(-(bf2f(a.y) + bf2f(c.y))));
  p += q.z / (1.f + expf(-(bf2f(a.z) + bf2f(c.z))));
  p += q.w / (1.f + expf(-(bf2f(a.w) + bf2f(c.w))));
#pragma unroll
  for (int off = 32; off > 0; off >>= 1) p += __shfl_down(p, off);
  if (lane == 0) alpha[i] = p + qb[0];
}
// s_g -> shin[:, 256:512]
__global__ void k_sg(const float* __restrict__ alpha, const unsigned short* __restrict__ h2b,
                     unsigned short* __restrict__ shin) {
  int b = blockIdx.x, c = threadIdx.x;
  float s = 0.f;
#pragma unroll
  for (int j = 0; j < NPER; j++)
    s += alpha[b * NPER + j] * bf2f(h2b[((size_t)b * NPER + j) * 256 + c]);
  shin[(size_t)b * 512 + 256 + c] = f2bf(s);
}
__global__ void k_edges(const int* __restrict__ e, float* __restrict__ out) {
  int i = blockIdx.x * 256 + threadIdx.x;
  if (i < 2 * NROWS) out[i] = (float)e[i];
}

// ---------------- NT MFMA GEMM: C[M,N] = A[M,K] * B[N,K]^T (+bias[col]) ----------------
// 128x128 tile, 256 threads = 4 waves (2x2), each wave 64x64 via 4x4 of 16x16x32 MFMA.
// A,B bf16 row-major. Verified gfx950 layouts (m89):
//   A/B frag: m|n = lane&15, k = (lane>>4)*8 + j ; C/D: col = lane&15, row = (lane>>4)*4 + reg.
template <bool OUT_BF16>
__global__ __launch_bounds__(256) void k_gemm_nt(
    const unsigned short* __restrict__ A, int lda,
    const unsigned short* __restrict__ Bm, int ldb,
    const unsigned short* __restrict__ bias,
    void* __restrict__ C, int ldc, int M, int N, int K) {
  __shared__ __align__(16) unsigned short As[128 * 32];
  __shared__ __align__(16) unsigned short Bs[128 * 32];
  const int tid = threadIdx.x;
  const int wid = tid >> 6, lane = tid & 63;
  const int quad = lane >> 4, l15 = lane & 15;
  const int m0 = blockIdx.x * 128, n0 = blockIdx.y * 128;
  const int wm = (wid & 1) * 64, wn = (wid >> 1) * 64;
  f32x4 acc[4][4] = {};
  const int lrow = tid >> 2;            // 0..63
  const int lcol = (tid & 3) * 8;       // 0,8,16,24
  const size_t ar0 = (size_t)min(m0 + lrow, M - 1) * lda + lcol;
  const size_t ar1 = (size_t)min(m0 + lrow + 64, M - 1) * lda + lcol;
  const size_t br0 = (size_t)min(n0 + lrow, N - 1) * ldb + lcol;
  const size_t br1 = (size_t)min(n0 + lrow + 64, N - 1) * ldb + lcol;
  const int ak = quad * 8;
  for (int k0 = 0; k0 < K; k0 += 32) {
    *(float4*)&As[(size_t)tid * 8]        = *(const float4*)&A[ar0 + k0];
    *(float4*)&As[2048 + (size_t)tid * 8] = *(const float4*)&A[ar1 + k0];
    *(float4*)&Bs[(size_t)tid * 8]        = *(const float4*)&Bm[br0 + k0];
    *(float4*)&Bs[2048 + (size_t)tid * 8] = *(const float4*)&Bm[br1 + k0];
    __syncthreads();
    bf16x8 af[4], bfv[4];
#pragma unroll
    for (int mi = 0; mi < 4; mi++) af[mi] = *(const bf16x8*)&As[(wm + mi * 16 + l15) * 32 + ak];
#pragma unroll
    for (int ni = 0; ni < 4; ni++) bfv[ni] = *(const bf16x8*)&Bs[(wn + ni * 16 + l15) * 32 + ak];
#pragma unroll
    for (int mi = 0; mi < 4; mi++)
#pragma unroll
      for (int ni = 0; ni < 4; ni++)
        acc[mi][ni] = __builtin_amdgcn_mfma_f32_16x16x32_bf16(af[mi], bfv[ni], acc[mi][ni], 0, 0, 0);
    __syncthreads();
  }
#pragma unroll
  for (int mi = 0; mi < 4; mi++) {
    const int gr0 = m0 + wm + mi * 16 + quad * 4;
#pragma unroll
    for (int ni = 0; ni < 4; ni++) {
      const int gc = n0 + wn + ni * 16 + l15;
      if (gc >= N) continue;
      const float bv = bias ? bf2f(bias[gc]) : 0.f;
#pragma unroll
      for (int r = 0; r < 4; r++) {
        const int gr = gr0 + r;
        if (gr < M) {
          const float v = acc[mi][ni][r] + bv;
          if (OUT_BF16) ((unsigned short*)C)[(size_t)gr * ldc + gc] = f2bf(v);
          else          ((float*)C)[(size_t)gr * ldc + gc] = v;
        }
      }
    }
  }
}

extern "C" void kernel_launch(void* const* d_in, const int* in_sizes, int n_in,
                              void* d_out, int out_size, void* d_ws, size_t ws_size,
                              hipStream_t stream) {
  const int* x     = (const int*)d_in[0];
  const int* batch = (const int*)d_in[1];
  const int* eidx  = (const int*)d_in[2];
  const int* fg    = (const int*)d_in[3];
  const float* emb   = (const float*)d_in[4];    // FLOAT32 inputs (round-1 NaN proved this)
  const float* ggnnW = (const float*)d_in[5];
  const float* Wih   = (const float*)d_in[6];
  const float* Whh   = (const float*)d_in[7];
  const float* bih   = (const float*)d_in[8];
  const float* bhh   = (const float*)d_in[9];
  const float* W1w   = (const float*)d_in[10];
  const float* W1b   = (const float*)d_in[11];
  const float* W2w   = (const float*)d_in[12];
  const float* W2b   = (const float*)d_in[13];
  const float* qw    = (const float*)d_in[14];
  const float* qb    = (const float*)d_in[15];
  const float* W3w   = (const float*)d_in[16];
  const float* W3b   = (const float*)d_in[17];

  char* w = (char*)d_ws;
  size_t off = 0;
  auto alloc = [&](size_t bytes) { char* p = w + off; off += (bytes + 511) & ~(size_t)511; return p; };
  // S + Sb are dead before the gi GEMM runs -> giC overlays them (exact fit).
  float*          S    = (float*)alloc((size_t)NROWS * HDIM * 4);        // 12.58 MB
  unsigned short* Sb   = (unsigned short*)alloc((size_t)NROWS * HDIM * 2); // 6.29 MB
  unsigned short* giC  = (unsigned short*)S;                             // NROWS*768*2 = 18.87 MB overlay
  int*            map  = (int*)alloc((size_t)NNODE * 4);
  unsigned short* A2   = (unsigned short*)alloc((size_t)NROWS * HDIM * 2);
  unsigned short* t2   = A2;                                             // A2 dead after k_gather
  unsigned short* aggC = (unsigned short*)alloc((size_t)NROWS * HDIM * 2);
  unsigned short* embC = (unsigned short*)alloc((size_t)NROWS * HDIM * 2);
  unsigned short* embB = (unsigned short*)alloc((size_t)NNODE * HDIM * 2); // 25.6 MB
  unsigned short* WTb  = (unsigned short*)alloc((size_t)CV_WT * 2);
  unsigned short* WihB = (unsigned short*)alloc((size_t)CV_WIH * 2);
  unsigned short* WhhB = (unsigned short*)alloc((size_t)CV_WHH * 2);
  unsigned short* W1wB = (unsigned short*)alloc((size_t)CV_W1 * 2);
  unsigned short* W2wB = (unsigned short*)alloc((size_t)CV_W2 * 2);
  unsigned short* W3wB = (unsigned short*)alloc((size_t)CV_W3 * 2);
  unsigned short* biasB= (unsigned short*)alloc((size_t)CV_BIAS * 2);
  unsigned short* ghC  = (unsigned short*)alloc((size_t)NROWS * 768 * 2); // 18.87 MB
  unsigned short* h2b  = (unsigned short*)alloc((size_t)NROWS * HDIM * 2);
  unsigned short* t1   = (unsigned short*)alloc((size_t)BSESS * HDIM * 2);
  float*          alpha = (float*)alloc((size_t)NROWS * 4);
  unsigned short* shin = (unsigned short*)alloc((size_t)BSESS * 512 * 2);
  unsigned short* shb  = (unsigned short*)alloc((size_t)BSESS * HDIM * 2);
  if (off > ws_size) return;  // fail visibly (all-zero out) rather than corrupt

  float* out_scores = (float*)d_out;                                  // [1024, 50000]
  float* out_h2     = out_scores + (size_t)BSESS * NNODE;             // [12288, 256]
  float* out_e      = out_h2 + (size_t)NROWS * HDIM;                  // [2, 12288]

  dim3 blk(256);
  k_zero_f4 <<<(NROWS * HDIM / 4 + 255) / 256, blk, 0, stream>>>((float4*)S, NROWS * HDIM / 4);
  k_init_map<<<(NNODE + 255) / 256, blk, 0, stream>>>(map);
  k_set_map <<<(NROWS + 255) / 256, blk, 0, stream>>>(x, map);
  k_conv    <<<(CV_TOTAL + 255) / 256, blk, 0, stream>>>(emb, ggnnW, Wih, Whh, W1w, W2w, W3w,
                bih, bhh, W1b, W2b, W3b, embB, WTb, WihB, WhhB, W1wB, W2wB, W3wB, biasB);
  k_scatter <<<EFULL / 4, blk, 0, stream>>>(fg, map, emb, S);
  k_f2bf_arr<<<NROWS * HDIM / 256, blk, 0, stream>>>(S, Sb, NROWS * HDIM);
  // agg = segsum(emb)@W  (linearity: segsum(emb@W) == segsum(emb)@W)
  k_gemm_nt<true><<<dim3(96, 2), blk, 0, stream>>>(Sb, HDIM, WTb, HDIM, nullptr, A2, HDIM, NROWS, HDIM, HDIM);
  k_gather  <<<NROWS, 64, 0, stream>>>(x, map, A2, emb, aggC, embC);
  // gi = aggC @ Wih^T + bih ; gh = embC @ Whh^T + bhh
  k_gemm_nt<true><<<dim3(96, 6), blk, 0, stream>>>(aggC, HDIM, WihB, HDIM, biasB, giC, 768, NROWS, 768, HDIM);
  k_gemm_nt<true><<<dim3(96, 6), blk, 0, stream>>>(embC, HDIM, WhhB, HDIM, biasB + 768, ghC, 768, NROWS, 768, HDIM);
  k_gru     <<<NROWS, blk, 0, stream>>>(giC, ghC, embC, h2b, out_h2);
  k_vn      <<<BSESS, blk, 0, stream>>>(h2b, shin);
  // t1 = v_n @ W1^T + W1_b ; t2 = h2 @ W2^T + W2_b
  k_gemm_nt<true><<<dim3(8, 2), blk, 0, stream>>>(shin, 512, W1wB, HDIM, biasB + 1536, t1, HDIM, BSESS, HDIM, HDIM);
  k_gemm_nt<true><<<dim3(96, 2), blk, 0, stream>>>(h2b, HDIM, W2wB, HDIM, biasB + 1792, t2, HDIM, NROWS, HDIM, HDIM);
  k_alpha   <<<NROWS, 64, 0, stream>>>(t1, t2, batch, qw, qb, alpha);
  k_sg      <<<BSESS, blk, 0, stream>>>(alpha, h2b, shin);
  // s_h = [v_n, s_g] @ W3^T + W3_b
  k_gemm_nt<true><<<dim3(8, 2), blk, 0, stream>>>(shin, 512, W3wB, 512, biasB + 2048, shb, HDIM, BSESS, HDIM, 512);
  // scores = s_h @ emb^T  -> d_out (float32)
  k_gemm_nt<false><<<dim3(8, 391), blk, 0, stream>>>(shb, HDIM, embB, HDIM, nullptr, out_scores, NNODE, BSESS, NNODE, HDIM);
  k_edges   <<<(2 * NROWS + 255) / 256, blk, 0, stream>>>(eidx, out_e);
}